// Round 2
// baseline (576.967 us; speedup 1.0000x reference)
//
#include <hip/hip_runtime.h>
#include <hip/hip_bf16.h>

#define NB 32
#define TQ 1024
#define TK 1024
#define DKD 64
#define TILE_Q 16
#define KT 32
#define MASK_FILL -4294967295.0f
#define LDP 68  // 64 + 4 pad -> odd 16B-unit row stride, b128 conflict-free

__global__ __launch_bounds__(256, 2)
void attn_fused_kernel(const float* __restrict__ Kp,
                       const float* __restrict__ Vp,
                       const float* __restrict__ Qp,
                       const int* __restrict__ Mp,
                       const float* __restrict__ QMp,
                       float* __restrict__ out_res,
                       float* __restrict__ out_attn)
{
    __shared__ float q_s[TILE_Q][LDP];
    __shared__ float k_s[KT][LDP];      // shared between K-tiles and V-tiles
    __shared__ float sc[TILE_Q][TK];    // 64 KB score/attn rows

    const int tid = threadIdx.x;
    const int b  = blockIdx.x >> 6;     // 64 q-tiles per batch
    const int qt = blockIdx.x & 63;
    const int q0g = qt * TILE_Q;

    // ---- load Q tile (16x64 fp32) into LDS ----
    {
        int row = tid >> 4;            // 0..15
        int c4  = (tid & 15) * 4;      // 0..60
        float4 v = *(const float4*)(Qp + ((size_t)b * TQ + q0g + row) * DKD + c4);
        *(float4*)&q_s[row][c4] = v;
    }

    const int kq = tid & 31;   // k within K-tile
    const int qa = tid >> 5;   // 0..7 (thread also handles qa+8)

    // ---- QK^T + mask -> scores in LDS ----
    for (int kt = 0; kt < TK; kt += KT) {
        __syncthreads();  // protect k_s reuse
        #pragma unroll
        for (int i = 0; i < 2; i++) {
            int idx = tid + i * 256;
            int row = idx >> 4;        // 0..31
            int c4  = (idx & 15) * 4;
            float4 v = *(const float4*)(Kp + ((size_t)b * TK + kt + row) * DKD + c4);
            *(float4*)&k_s[row][c4] = v;
        }
        __syncthreads();

        float a0 = 0.f, a1 = 0.f;
        #pragma unroll
        for (int d = 0; d < DKD; d += 4) {
            float4 kv = *(const float4*)&k_s[kq][d];
            float4 v0 = *(const float4*)&q_s[qa][d];
            float4 v1 = *(const float4*)&q_s[qa + 8][d];
            a0 = fmaf(v0.x, kv.x, a0); a0 = fmaf(v0.y, kv.y, a0);
            a0 = fmaf(v0.z, kv.z, a0); a0 = fmaf(v0.w, kv.w, a0);
            a1 = fmaf(v1.x, kv.x, a1); a1 = fmaf(v1.y, kv.y, a1);
            a1 = fmaf(v1.z, kv.z, a1); a1 = fmaf(v1.w, kv.w, a1);
        }
        const int kg = kt + kq;
        const int m0 = Mp[((size_t)b * TQ + q0g + qa) * TK + kg];
        const int m1 = Mp[((size_t)b * TQ + q0g + qa + 8) * TK + kg];
        sc[qa][kg]     = m0 ? MASK_FILL : a0 * 0.125f;
        sc[qa + 8][kg] = m1 ? MASK_FILL : a1 * 0.125f;
    }
    __syncthreads();

    // ---- softmax (per wave, 4 rows each) + query_mask + attn output ----
    {
        const int wave = tid >> 6;
        const int lane = tid & 63;
        for (int r = 0; r < 4; r++) {
            const int q = wave * 4 + r;
            float* row = sc[q];
            float m = -INFINITY;
            #pragma unroll
            for (int i = 0; i < 16; i++) m = fmaxf(m, row[lane + i * 64]);
            #pragma unroll
            for (int off = 32; off >= 1; off >>= 1) m = fmaxf(m, __shfl_xor(m, off, 64));

            float e[16];
            float s = 0.f;
            #pragma unroll
            for (int i = 0; i < 16; i++) {
                e[i] = __expf(row[lane + i * 64] - m);
                s += e[i];
            }
            #pragma unroll
            for (int off = 32; off >= 1; off >>= 1) s += __shfl_xor(s, off, 64);

            const float qm = QMp[(size_t)b * TQ + q0g + q];
            const float scale = qm / s;
            float* oa = out_attn + ((size_t)b * TQ + q0g + q) * TK;
            #pragma unroll
            for (int i = 0; i < 16; i++) {
                float v = e[i] * scale;
                row[lane + i * 64] = v;           // attn for PV phase
                oa[lane + i * 64] = v;            // attn output (fp32)
            }
        }
    }
    __syncthreads();

    // ---- PV: result[q][d] = sum_k attn[q][k] * V[k][d] ----
    const int x  = tid & 15;   // d4 group
    const int qp = tid >> 4;   // 0..15
    float ax = 0.f, ay = 0.f, az = 0.f, aw = 0.f;
    for (int kt = 0; kt < TK; kt += KT) {
        __syncthreads();
        #pragma unroll
        for (int i = 0; i < 2; i++) {
            int idx = tid + i * 256;
            int row = idx >> 4;
            int c4  = (idx & 15) * 4;
            float4 v = *(const float4*)(Vp + ((size_t)b * TK + kt + row) * DKD + c4);
            *(float4*)&k_s[row][c4] = v;
        }
        __syncthreads();

        #pragma unroll 8
        for (int k = 0; k < KT; k++) {
            float a = sc[qp][kt + k];
            float4 vv = *(const float4*)&k_s[k][x * 4];
            ax = fmaf(a, vv.x, ax);
            ay = fmaf(a, vv.y, ay);
            az = fmaf(a, vv.z, az);
            aw = fmaf(a, vv.w, aw);
        }
    }

    {
        float4 r4 = make_float4(ax, ay, az, aw);
        *(float4*)(out_res + ((size_t)b * TQ + q0g + qp) * DKD + x * 4) = r4;
    }
}

extern "C" void kernel_launch(void* const* d_in, const int* in_sizes, int n_in,
                              void* d_out, int out_size, void* d_ws, size_t ws_size,
                              hipStream_t stream) {
    const float* Kp  = (const float*)d_in[0];
    const float* Vp  = (const float*)d_in[1];
    const float* Qp  = (const float*)d_in[2];
    const int*   Mp  = (const int*)d_in[3];
    const float* QMp = (const float*)d_in[4];

    float* out      = (float*)d_out;
    float* out_res  = out;                              // [B,TQ,DK]
    float* out_attn = out + (size_t)NB * TQ * DKD;      // [B,TQ,TK]

    dim3 grid(NB * (TQ / TILE_Q));   // 2048 blocks
    dim3 block(256);
    attn_fused_kernel<<<grid, block, 0, stream>>>(Kp, Vp, Qp, Mp, QMp, out_res, out_attn);
}

// Round 3
// 366.317 us; speedup vs baseline: 1.5750x; 1.5750x over previous
//
#include <hip/hip_runtime.h>
#include <hip/hip_bf16.h>

#define NB 32
#define TQ 1024
#define TK 1024
#define DKD 64
#define TILE_Q 16
#define MASK_FILL -4294967295.0f
#define SCW 1028  // sc row stride in floats (+4 pad: 2-way bank alias = free)

typedef __attribute__((ext_vector_type(8))) short short8;
typedef __attribute__((ext_vector_type(4))) float floatx4;

union U8 { short8 s; unsigned int u[4]; };

// Split f32 -> bf16 hi + bf16 lo (hi truncated, lo = f - hi, truncated).
// Residual error ~2^-17 relative.
__device__ __forceinline__ void cvt_hilo(const float4 a, const float4 b,
                                         short8& hi, short8& lo) {
    const float f[8] = {a.x, a.y, a.z, a.w, b.x, b.y, b.z, b.w};
    U8 H, L;
#pragma unroll
    for (int i = 0; i < 4; i++) {
        unsigned u0 = __float_as_uint(f[2 * i]);
        unsigned u1 = __float_as_uint(f[2 * i + 1]);
        unsigned h0 = u0 & 0xffff0000u;
        unsigned h1 = u1 & 0xffff0000u;
        H.u[i] = h1 | (h0 >> 16);
        float l0 = f[2 * i]     - __uint_as_float(h0);
        float l1 = f[2 * i + 1] - __uint_as_float(h1);
        L.u[i] = (__float_as_uint(l1) & 0xffff0000u) | (__float_as_uint(l0) >> 16);
    }
    hi = H.s;
    lo = L.s;
}

__device__ __forceinline__ unsigned short f2bf_rn(float f) {
    __hip_bfloat16 h = __float2bfloat16(f);  // round-to-nearest
    return *reinterpret_cast<unsigned short*>(&h);
}

__global__ __launch_bounds__(256, 2)
void attn_mfma_kernel(const float* __restrict__ Kp,
                      const float* __restrict__ Vp,
                      const float* __restrict__ Qp,
                      const int* __restrict__ Mp,
                      const float* __restrict__ QMp,
                      float* __restrict__ out_res,
                      float* __restrict__ out_attn)
{
    // 65792 B scores (fp32); first 2048 B of each row reused as packed bf16 P
    __shared__ float sc[TILE_Q][SCW];
    // per-wave V^T slice: [wave][d within n-tile][k of 64-tile], 144 B rows
    __shared__ unsigned short vt[4][16][72];

    const int tid  = threadIdx.x;
    const int lane = tid & 63;
    const int wave = tid >> 6;
    const int quad = lane >> 4;
    const int r16  = lane & 15;

    const int b  = blockIdx.x >> 6;
    const int q0 = (blockIdx.x & 63) * TILE_Q;
    const size_t bq = (size_t)b * TQ + q0;

    // ---- Q fragments in registers (A-operand: A[m=lane&15][k=quad*8+j]) ----
    short8 qhi0, qlo0, qhi1, qlo1;
    {
        const float* qrow = Qp + (bq + r16) * DKD + quad * 8;
        float4 a0 = *(const float4*)(qrow);
        float4 a1 = *(const float4*)(qrow + 4);
        float4 b0 = *(const float4*)(qrow + 32);
        float4 b1 = *(const float4*)(qrow + 36);
        cvt_hilo(a0, a1, qhi0, qlo0);
        cvt_hilo(b0, b1, qhi1, qlo1);
    }

    // ---- QK^T: wave w owns k-columns [w*256, w*256+256) ----
    const int kt0 = wave * 256;
    {
        const float* krow0 = Kp + ((size_t)b * TK + kt0 + r16) * DKD + quad * 8;
        float4 c0 = *(const float4*)(krow0);
        float4 c1 = *(const float4*)(krow0 + 4);
        float4 c2 = *(const float4*)(krow0 + 32);
        float4 c3 = *(const float4*)(krow0 + 36);
        int mc0 = Mp[(bq + quad * 4 + 0) * TK + kt0 + r16];
        int mc1 = Mp[(bq + quad * 4 + 1) * TK + kt0 + r16];
        int mc2 = Mp[(bq + quad * 4 + 2) * TK + kt0 + r16];
        int mc3 = Mp[(bq + quad * 4 + 3) * TK + kt0 + r16];

        for (int i = 0; i < 16; i++) {
            const int kt  = kt0 + i * 16;
            const int ktn = kt0 + ((i + 1) & 15) * 16;  // prefetch (wraps on last)
            const float* krown = Kp + ((size_t)b * TK + ktn + r16) * DKD + quad * 8;
            float4 n0 = *(const float4*)(krown);
            float4 n1 = *(const float4*)(krown + 4);
            float4 n2 = *(const float4*)(krown + 32);
            float4 n3 = *(const float4*)(krown + 36);
            int mn0 = Mp[(bq + quad * 4 + 0) * TK + ktn + r16];
            int mn1 = Mp[(bq + quad * 4 + 1) * TK + ktn + r16];
            int mn2 = Mp[(bq + quad * 4 + 2) * TK + ktn + r16];
            int mn3 = Mp[(bq + quad * 4 + 3) * TK + ktn + r16];

            short8 khi0, klo0, khi1, klo1;
            cvt_hilo(c0, c1, khi0, klo0);
            cvt_hilo(c2, c3, khi1, klo1);

            floatx4 acc = {0.f, 0.f, 0.f, 0.f};
            acc = __builtin_amdgcn_mfma_f32_16x16x32_bf16(qhi0, khi0, acc, 0, 0, 0);
            acc = __builtin_amdgcn_mfma_f32_16x16x32_bf16(qlo0, khi0, acc, 0, 0, 0);
            acc = __builtin_amdgcn_mfma_f32_16x16x32_bf16(qhi0, klo0, acc, 0, 0, 0);
            acc = __builtin_amdgcn_mfma_f32_16x16x32_bf16(qhi1, khi1, acc, 0, 0, 0);
            acc = __builtin_amdgcn_mfma_f32_16x16x32_bf16(qlo1, khi1, acc, 0, 0, 0);
            acc = __builtin_amdgcn_mfma_f32_16x16x32_bf16(qhi1, klo1, acc, 0, 0, 0);

            // C/D layout: col=lane&15 (k), row=quad*4+reg (q)
            const int col = kt + r16;
            const int msk[4] = {mc0, mc1, mc2, mc3};
#pragma unroll
            for (int r = 0; r < 4; r++) {
                const int row = quad * 4 + r;
                sc[row][col] = msk[r] ? MASK_FILL : acc[r] * 0.125f;
            }
            c0 = n0; c1 = n1; c2 = n2; c3 = n3;
            mc0 = mn0; mc1 = mn1; mc2 = mn2; mc3 = mn3;
        }
    }
    __syncthreads();

    // ---- softmax + query_mask; write attn (fp32, global) + P (bf16, LDS) ----
    for (int r = 0; r < 4; r++) {
        const int q = wave * 4 + r;
        float* row = sc[q];
        float m = -INFINITY;
#pragma unroll
        for (int i = 0; i < 16; i++) m = fmaxf(m, row[lane + i * 64]);
#pragma unroll
        for (int off = 32; off >= 1; off >>= 1) m = fmaxf(m, __shfl_xor(m, off, 64));

        float e[16];
        float s = 0.f;
#pragma unroll
        for (int i = 0; i < 16; i++) {
            e[i] = __expf(row[lane + i * 64] - m);
            s += e[i];
        }
#pragma unroll
        for (int off = 32; off >= 1; off >>= 1) s += __shfl_xor(s, off, 64);

        const float qm = QMp[bq + q];
        const float scale = qm / s;
        float* oa = out_attn + (bq + q) * TK;
        unsigned short* prow = reinterpret_cast<unsigned short*>(&sc[q][0]);
#pragma unroll
        for (int i = 0; i < 16; i++) {
            float v = e[i] * scale;
            oa[lane + i * 64] = v;            // attn output, fp32
            prow[lane + i * 64] = f2bf_rn(v); // packed P for PV (in-place, safe:
                                              // all reads of this row retired)
        }
    }
    __syncthreads();

    // ---- PV: wave w owns output d-columns [w*16, w*16+16), full k ----
    const int dsl = wave * 16;
    floatx4 racc = {0.f, 0.f, 0.f, 0.f};
    {
        const float* vr = Vp + ((size_t)b * TK + lane) * DKD + dsl;
        float4 v0 = *(const float4*)(vr);
        float4 v1 = *(const float4*)(vr + 4);
        float4 v2 = *(const float4*)(vr + 8);
        float4 v3 = *(const float4*)(vr + 12);

        for (int kt = 0; kt < TK; kt += 64) {
            const int ktn = (kt + 64) & (TK - 1);  // prefetch (wraps on last)
            const float* vrn = Vp + ((size_t)b * TK + ktn + lane) * DKD + dsl;
            float4 n0 = *(const float4*)(vrn);
            float4 n1 = *(const float4*)(vrn + 4);
            float4 n2 = *(const float4*)(vrn + 8);
            float4 n3 = *(const float4*)(vrn + 12);

            // stage V^T slice: vt[w][d][k] = bf16(V[kt+k][dsl+d]), k = lane
            const float f[16] = {v0.x, v0.y, v0.z, v0.w, v1.x, v1.y, v1.z, v1.w,
                                 v2.x, v2.y, v2.z, v2.w, v3.x, v3.y, v3.z, v3.w};
#pragma unroll
            for (int dj = 0; dj < 16; dj++) vt[wave][dj][lane] = f2bf_rn(f[dj]);

            __syncthreads();  // drains own ds_writes; orders vs prev-iter reads

#pragma unroll
            for (int ks = 0; ks < 2; ks++) {
                const int koff = ks * 32;
                // A-frag: P[q=lane&15][kt+koff+quad*8 .. +8] (packed bf16 in sc)
                const unsigned short* pbase =
                    reinterpret_cast<const unsigned short*>(&sc[r16][0]);
                short8 pf = *(const short8*)(pbase + kt + koff + quad * 8);
                // B-frag: V[kt+koff+quad*8+j][dsl+lane&15] via vt[w][r16][...]
                short8 vf = *(const short8*)(&vt[wave][r16][koff + quad * 8]);
                racc = __builtin_amdgcn_mfma_f32_16x16x32_bf16(pf, vf, racc, 0, 0, 0);
            }
            v0 = n0; v1 = n1; v2 = n2; v3 = n3;
        }
    }

#pragma unroll
    for (int r = 0; r < 4; r++) {
        out_res[(bq + quad * 4 + r) * DKD + dsl + r16] = racc[r];
    }
}

extern "C" void kernel_launch(void* const* d_in, const int* in_sizes, int n_in,
                              void* d_out, int out_size, void* d_ws, size_t ws_size,
                              hipStream_t stream) {
    const float* Kp  = (const float*)d_in[0];
    const float* Vp  = (const float*)d_in[1];
    const float* Qp  = (const float*)d_in[2];
    const int*   Mp  = (const int*)d_in[3];
    const float* QMp = (const float*)d_in[4];

    float* out      = (float*)d_out;
    float* out_res  = out;                              // [B,TQ,DK]
    float* out_attn = out + (size_t)NB * TQ * DKD;      // [B,TQ,TK]

    dim3 grid(NB * (TQ / TILE_Q));   // 2048 blocks
    dim3 block(256);
    attn_mfma_kernel<<<grid, block, 0, stream>>>(Kp, Vp, Qp, Mp, QMp, out_res, out_attn);
}

// Round 4
// 355.913 us; speedup vs baseline: 1.6211x; 1.0292x over previous
//
#include <hip/hip_runtime.h>
#include <hip/hip_bf16.h>

#define NB 32
#define TQ 1024
#define TK 1024
#define DKD 64
#define TILE_Q 16
#define MASK_FILL -4294967295.0f
#define PSTR 1032  // P row stride in shorts: 129 x 16B units, ≡1 mod 8 -> uniform b128 bank spread

typedef __attribute__((ext_vector_type(8))) short short8;
typedef __attribute__((ext_vector_type(4))) float floatx4;

union U8 { short8 s; unsigned int u[4]; };

// Split f32 -> bf16 hi + bf16 lo (hi truncated, lo = f - hi, truncated).
__device__ __forceinline__ void cvt_hilo(const float4 a, const float4 b,
                                         short8& hi, short8& lo) {
    const float f[8] = {a.x, a.y, a.z, a.w, b.x, b.y, b.z, b.w};
    U8 H, L;
#pragma unroll
    for (int i = 0; i < 4; i++) {
        unsigned u0 = __float_as_uint(f[2 * i]);
        unsigned u1 = __float_as_uint(f[2 * i + 1]);
        unsigned h0 = u0 & 0xffff0000u;
        unsigned h1 = u1 & 0xffff0000u;
        H.u[i] = h1 | (h0 >> 16);
        float l0 = f[2 * i]     - __uint_as_float(h0);
        float l1 = f[2 * i + 1] - __uint_as_float(h1);
        L.u[i] = (__float_as_uint(l1) & 0xffff0000u) | (__float_as_uint(l0) >> 16);
    }
    hi = H.s;
    lo = L.s;
}

__device__ __forceinline__ unsigned short f2bf_rn(float f) {
    __hip_bfloat16 h = __float2bfloat16(f);  // RTNE
    return *reinterpret_cast<unsigned short*>(&h);
}

__global__ __launch_bounds__(256, 3)
void attn_mfma_kernel(const float* __restrict__ Kp,
                      const float* __restrict__ Vp,
                      const float* __restrict__ Qp,
                      const int* __restrict__ Mp,
                      const float* __restrict__ QMp,
                      float* __restrict__ out_res,
                      float* __restrict__ out_attn)
{
    __shared__ unsigned short Pb[TILE_Q * PSTR];  // 33 KB packed-bf16 attn
    __shared__ float redm[4][16];                 // per-wave row-max partials
    __shared__ float reds[4][16];                 // per-wave row-sum partials

    const int tid  = threadIdx.x;
    const int lane = tid & 63;
    const int wave = tid >> 6;
    const int quad = lane >> 4;
    const int r16  = lane & 15;

    const int b  = blockIdx.x >> 6;
    const int q0 = (blockIdx.x & 63) * TILE_Q;
    const size_t bq = (size_t)b * TQ + q0;

    // ---- Q fragments (A-operand: A[m=r16][k=quad*8+j]) ----
    short8 qhi0, qlo0, qhi1, qlo1;
    {
        const float* qrow = Qp + (bq + r16) * DKD + quad * 8;
        float4 a0 = *(const float4*)(qrow);
        float4 a1 = *(const float4*)(qrow + 4);
        float4 b0 = *(const float4*)(qrow + 32);
        float4 b1 = *(const float4*)(qrow + 36);
        cvt_hilo(a0, a1, qhi0, qlo0);
        cvt_hilo(b0, b1, qhi1, qlo1);
    }

    // ---- QK^T: wave w owns k-slab [w*256, w*256+256); scores -> registers ----
    const int kt0 = wave * 256;
    floatx4 sreg[16];
    {
        const float* krow0 = Kp + ((size_t)b * TK + kt0 + r16) * DKD + quad * 8;
        float4 c0 = *(const float4*)(krow0);
        float4 c1 = *(const float4*)(krow0 + 4);
        float4 c2 = *(const float4*)(krow0 + 32);
        float4 c3 = *(const float4*)(krow0 + 36);
        int mc0 = Mp[(bq + quad * 4 + 0) * TK + kt0 + r16];
        int mc1 = Mp[(bq + quad * 4 + 1) * TK + kt0 + r16];
        int mc2 = Mp[(bq + quad * 4 + 2) * TK + kt0 + r16];
        int mc3 = Mp[(bq + quad * 4 + 3) * TK + kt0 + r16];

#pragma unroll
        for (int i = 0; i < 16; i++) {
            const int ktn = kt0 + ((i + 1) & 15) * 16;  // wraps on last (harmless)
            const float* krown = Kp + ((size_t)b * TK + ktn + r16) * DKD + quad * 8;
            float4 n0 = *(const float4*)(krown);
            float4 n1 = *(const float4*)(krown + 4);
            float4 n2 = *(const float4*)(krown + 32);
            float4 n3 = *(const float4*)(krown + 36);
            int mn0 = Mp[(bq + quad * 4 + 0) * TK + ktn + r16];
            int mn1 = Mp[(bq + quad * 4 + 1) * TK + ktn + r16];
            int mn2 = Mp[(bq + quad * 4 + 2) * TK + ktn + r16];
            int mn3 = Mp[(bq + quad * 4 + 3) * TK + ktn + r16];

            short8 khi0, klo0, khi1, klo1;
            cvt_hilo(c0, c1, khi0, klo0);
            cvt_hilo(c2, c3, khi1, klo1);

            floatx4 acc = {0.f, 0.f, 0.f, 0.f};
            acc = __builtin_amdgcn_mfma_f32_16x16x32_bf16(qhi0, khi0, acc, 0, 0, 0);
            acc = __builtin_amdgcn_mfma_f32_16x16x32_bf16(qlo0, khi0, acc, 0, 0, 0);
            acc = __builtin_amdgcn_mfma_f32_16x16x32_bf16(qhi0, klo0, acc, 0, 0, 0);
            acc = __builtin_amdgcn_mfma_f32_16x16x32_bf16(qhi1, khi1, acc, 0, 0, 0);
            acc = __builtin_amdgcn_mfma_f32_16x16x32_bf16(qlo1, khi1, acc, 0, 0, 0);
            acc = __builtin_amdgcn_mfma_f32_16x16x32_bf16(qhi1, klo1, acc, 0, 0, 0);

            floatx4 sv;
            sv[0] = mc0 ? MASK_FILL : acc[0] * 0.125f;
            sv[1] = mc1 ? MASK_FILL : acc[1] * 0.125f;
            sv[2] = mc2 ? MASK_FILL : acc[2] * 0.125f;
            sv[3] = mc3 ? MASK_FILL : acc[3] * 0.125f;
            sreg[i] = sv;

            c0 = n0; c1 = n1; c2 = n2; c3 = n3;
            mc0 = mn0; mc1 = mn1; mc2 = mn2; mc3 = mn3;
        }
    }

    // ---- softmax in C-layout: quad owns rows quad*4..quad*4+3 of its slab ----
    float lmax[4] = {-INFINITY, -INFINITY, -INFINITY, -INFINITY};
#pragma unroll
    for (int i = 0; i < 16; i++) {
#pragma unroll
        for (int r = 0; r < 4; r++) lmax[r] = fmaxf(lmax[r], sreg[i][r]);
    }
#pragma unroll
    for (int off = 8; off >= 1; off >>= 1) {
#pragma unroll
        for (int r = 0; r < 4; r++)
            lmax[r] = fmaxf(lmax[r], __shfl_xor(lmax[r], off, 64));
    }
    if (r16 == 0) {
#pragma unroll
        for (int r = 0; r < 4; r++) redm[wave][quad * 4 + r] = lmax[r];
    }
    __syncthreads();

    float gmax[4];
#pragma unroll
    for (int r = 0; r < 4; r++) {
        float m = redm[0][quad * 4 + r];
        m = fmaxf(m, redm[1][quad * 4 + r]);
        m = fmaxf(m, redm[2][quad * 4 + r]);
        m = fmaxf(m, redm[3][quad * 4 + r]);
        gmax[r] = m;
    }

    float lsum[4] = {0.f, 0.f, 0.f, 0.f};
#pragma unroll
    for (int i = 0; i < 16; i++) {
#pragma unroll
        for (int r = 0; r < 4; r++) lsum[r] += __expf(sreg[i][r] - gmax[r]);
    }
#pragma unroll
    for (int off = 8; off >= 1; off >>= 1) {
#pragma unroll
        for (int r = 0; r < 4; r++) lsum[r] += __shfl_xor(lsum[r], off, 64);
    }
    if (r16 == 0) {
#pragma unroll
        for (int r = 0; r < 4; r++) reds[wave][quad * 4 + r] = lsum[r];
    }
    __syncthreads();

    float scale[4];
#pragma unroll
    for (int r = 0; r < 4; r++) {
        float s = reds[0][quad * 4 + r] + reds[1][quad * 4 + r] +
                  reds[2][quad * 4 + r] + reds[3][quad * 4 + r];
        scale[r] = QMp[bq + quad * 4 + r] / s;
    }

    // ---- write attn (fp32 global) + P (bf16 LDS) ----
#pragma unroll
    for (int i = 0; i < 16; i++) {
        const int col = kt0 + i * 16 + r16;
#pragma unroll
        for (int r = 0; r < 4; r++) {
            float v = __expf(sreg[i][r] - gmax[r]) * scale[r];
            out_attn[(bq + quad * 4 + r) * TK + col] = v;
            Pb[(quad * 4 + r) * PSTR + col] = f2bf_rn(v);
        }
    }
    __syncthreads();

    // ---- PV: wave w owns d-columns [w*16, w*16+16); V gathered from global ----
    const int dsl = wave * 16;
    floatx4 racc = {0.f, 0.f, 0.f, 0.f};
    {
        // lane reads V[k = c*32 + quad*8 + j][dsl + r16]
        const float* vbase = Vp + ((size_t)b * TK + quad * 8) * DKD + dsl + r16;
        float cur[8];
#pragma unroll
        for (int j = 0; j < 8; j++) cur[j] = vbase[j * DKD];

#pragma unroll 2
        for (int c = 0; c < 32; c++) {
            const int cn = (c + 1) & 31;  // wraps on last (harmless reload)
            float nxt[8];
#pragma unroll
            for (int j = 0; j < 8; j++) nxt[j] = vbase[(cn * 32 + j) * DKD];

            U8 vf;
#pragma unroll
            for (int p = 0; p < 4; p++)
                vf.u[p] = ((unsigned)f2bf_rn(cur[2 * p + 1]) << 16) |
                          (unsigned)f2bf_rn(cur[2 * p]);

            short8 pf = *(const short8*)(&Pb[r16 * PSTR + c * 32 + quad * 8]);
            racc = __builtin_amdgcn_mfma_f32_16x16x32_bf16(pf, vf.s, racc, 0, 0, 0);

#pragma unroll
            for (int j = 0; j < 8; j++) cur[j] = nxt[j];
        }
    }

#pragma unroll
    for (int r = 0; r < 4; r++)
        out_res[(bq + quad * 4 + r) * DKD + dsl + r16] = racc[r];
}

extern "C" void kernel_launch(void* const* d_in, const int* in_sizes, int n_in,
                              void* d_out, int out_size, void* d_ws, size_t ws_size,
                              hipStream_t stream) {
    const float* Kp  = (const float*)d_in[0];
    const float* Vp  = (const float*)d_in[1];
    const float* Qp  = (const float*)d_in[2];
    const int*   Mp  = (const int*)d_in[3];
    const float* QMp = (const float*)d_in[4];

    float* out      = (float*)d_out;
    float* out_res  = out;                              // [B,TQ,DK]
    float* out_attn = out + (size_t)NB * TQ * DKD;      // [B,TQ,TK]

    dim3 grid(NB * (TQ / TILE_Q));   // 2048 blocks
    dim3 block(256);
    attn_mfma_kernel<<<grid, block, 0, stream>>>(Kp, Vp, Qp, Mp, QMp, out_res, out_attn);
}

// Round 5
// 352.838 us; speedup vs baseline: 1.6352x; 1.0087x over previous
//
#include <hip/hip_runtime.h>
#include <hip/hip_bf16.h>

#define NB 32
#define TQ 1024
#define TK 1024
#define DKD 64
#define TILE_Q 16
#define MASK_FILL -4294967295.0f
#define PSTR 1032  // P row stride in shorts: 129 x 16B units -> uniform b128 bank spread

typedef __attribute__((ext_vector_type(8))) short short8;
typedef __attribute__((ext_vector_type(4))) float floatx4;

union U8 { short8 s; unsigned int u[4]; };

// Split f32 -> bf16 hi + bf16 lo (hi truncated, lo = f - hi, truncated).
__device__ __forceinline__ void cvt_hilo(const float4 a, const float4 b,
                                         short8& hi, short8& lo) {
    const float f[8] = {a.x, a.y, a.z, a.w, b.x, b.y, b.z, b.w};
    U8 H, L;
#pragma unroll
    for (int i = 0; i < 4; i++) {
        unsigned u0 = __float_as_uint(f[2 * i]);
        unsigned u1 = __float_as_uint(f[2 * i + 1]);
        unsigned h0 = u0 & 0xffff0000u;
        unsigned h1 = u1 & 0xffff0000u;
        H.u[i] = h1 | (h0 >> 16);
        float l0 = f[2 * i]     - __uint_as_float(h0);
        float l1 = f[2 * i + 1] - __uint_as_float(h1);
        L.u[i] = (__float_as_uint(l1) & 0xffff0000u) | (__float_as_uint(l0) >> 16);
    }
    hi = H.s;
    lo = L.s;
}

__device__ __forceinline__ unsigned short f2bf_rn(float f) {
    __hip_bfloat16 h = __float2bfloat16(f);  // RTNE
    return *reinterpret_cast<unsigned short*>(&h);
}

__global__ __launch_bounds__(256, 4)
void attn_mfma_kernel(const float* __restrict__ Kp,
                      const float* __restrict__ Vp,
                      const float* __restrict__ Qp,
                      const int* __restrict__ Mp,
                      const float* __restrict__ QMp,
                      float* __restrict__ out_res,
                      float* __restrict__ out_attn)
{
    __shared__ unsigned short Pb[TILE_Q * PSTR];  // 33 KB packed-bf16 attn
    __shared__ float redm[4][16];
    __shared__ float reds[4][16];

    const int tid  = threadIdx.x;
    const int lane = tid & 63;
    const int wave = tid >> 6;
    const int quad = lane >> 4;
    const int r16  = lane & 15;

    const int b  = blockIdx.x >> 6;
    const int q0 = (blockIdx.x & 63) * TILE_Q;
    const size_t bq = (size_t)b * TQ + q0;
    const int kt0 = wave * 256;   // this wave's k-slab

    // ---- phase 0: burst-load ALL mask dwords for this wave's slab (64 loads
    // in flight = 256 B/lane), compress to a 64-bit register bitmask ----
    unsigned mb0 = 0, mb1 = 0;
    {
        const int* mp0 = Mp + (bq + quad * 4 + 0) * TK + kt0 + r16;
        const int* mp1 = mp0 + TK;
        const int* mp2 = mp1 + TK;
        const int* mp3 = mp2 + TK;
        int mv[64];
#pragma unroll
        for (int i = 0; i < 16; i++) {
            mv[i * 4 + 0] = mp0[i * 16];
            mv[i * 4 + 1] = mp1[i * 16];
            mv[i * 4 + 2] = mp2[i * 16];
            mv[i * 4 + 3] = mp3[i * 16];
        }
        unsigned lo = 0, hi = 0;
#pragma unroll
        for (int j = 0; j < 32; j++) lo |= ((unsigned)mv[j] & 1u) << j;
#pragma unroll
        for (int j = 0; j < 32; j++) hi |= ((unsigned)mv[32 + j] & 1u) << j;
        mb0 = lo;
        mb1 = hi;
    }

    // ---- Q fragments (A-operand: A[m=r16][k=quad*8+j]) ----
    short8 qhi0, qlo0, qhi1, qlo1;
    {
        const float* qrow = Qp + (bq + r16) * DKD + quad * 8;
        float4 a0 = *(const float4*)(qrow);
        float4 a1 = *(const float4*)(qrow + 4);
        float4 b0 = *(const float4*)(qrow + 32);
        float4 b1 = *(const float4*)(qrow + 36);
        cvt_hilo(a0, a1, qhi0, qlo0);
        cvt_hilo(b0, b1, qhi1, qlo1);
    }

    // ---- QK^T: scores -> registers; mask from bitmask regs ----
    floatx4 sreg[16];
    {
        const float* krow0 = Kp + ((size_t)b * TK + kt0 + r16) * DKD + quad * 8;
        float4 c0 = *(const float4*)(krow0);
        float4 c1 = *(const float4*)(krow0 + 4);
        float4 c2 = *(const float4*)(krow0 + 32);
        float4 c3 = *(const float4*)(krow0 + 36);

#pragma unroll
        for (int i = 0; i < 16; i++) {
            const int ktn = kt0 + ((i + 1) & 15) * 16;  // wraps on last (harmless)
            const float* krown = Kp + ((size_t)b * TK + ktn + r16) * DKD + quad * 8;
            float4 n0 = *(const float4*)(krown);
            float4 n1 = *(const float4*)(krown + 4);
            float4 n2 = *(const float4*)(krown + 32);
            float4 n3 = *(const float4*)(krown + 36);

            short8 khi0, klo0, khi1, klo1;
            cvt_hilo(c0, c1, khi0, klo0);
            cvt_hilo(c2, c3, khi1, klo1);

            floatx4 acc = {0.f, 0.f, 0.f, 0.f};
            acc = __builtin_amdgcn_mfma_f32_16x16x32_bf16(qhi0, khi0, acc, 0, 0, 0);
            acc = __builtin_amdgcn_mfma_f32_16x16x32_bf16(qlo0, khi0, acc, 0, 0, 0);
            acc = __builtin_amdgcn_mfma_f32_16x16x32_bf16(qhi0, klo0, acc, 0, 0, 0);
            acc = __builtin_amdgcn_mfma_f32_16x16x32_bf16(qhi1, khi1, acc, 0, 0, 0);
            acc = __builtin_amdgcn_mfma_f32_16x16x32_bf16(qlo1, khi1, acc, 0, 0, 0);
            acc = __builtin_amdgcn_mfma_f32_16x16x32_bf16(qhi1, klo1, acc, 0, 0, 0);

            const unsigned mw = (i < 8) ? mb0 : mb1;   // compile-time select
            floatx4 sv;
#pragma unroll
            for (int r = 0; r < 4; r++) {
                const unsigned bit = (mw >> ((i & 7) * 4 + r)) & 1u;
                sv[r] = bit ? MASK_FILL : acc[r] * 0.125f;
            }
            sreg[i] = sv;

            c0 = n0; c1 = n1; c2 = n2; c3 = n3;
        }
    }

    // ---- softmax in C-layout: quad owns rows quad*4..quad*4+3 of its slab ----
    float lmax[4] = {-INFINITY, -INFINITY, -INFINITY, -INFINITY};
#pragma unroll
    for (int i = 0; i < 16; i++) {
#pragma unroll
        for (int r = 0; r < 4; r++) lmax[r] = fmaxf(lmax[r], sreg[i][r]);
    }
#pragma unroll
    for (int off = 8; off >= 1; off >>= 1) {
#pragma unroll
        for (int r = 0; r < 4; r++)
            lmax[r] = fmaxf(lmax[r], __shfl_xor(lmax[r], off, 64));
    }
    if (r16 == 0) {
#pragma unroll
        for (int r = 0; r < 4; r++) redm[wave][quad * 4 + r] = lmax[r];
    }
    __syncthreads();

    float gmax[4];
#pragma unroll
    for (int r = 0; r < 4; r++) {
        float m = redm[0][quad * 4 + r];
        m = fmaxf(m, redm[1][quad * 4 + r]);
        m = fmaxf(m, redm[2][quad * 4 + r]);
        m = fmaxf(m, redm[3][quad * 4 + r]);
        gmax[r] = m;
    }

    float lsum[4] = {0.f, 0.f, 0.f, 0.f};
#pragma unroll
    for (int i = 0; i < 16; i++) {
#pragma unroll
        for (int r = 0; r < 4; r++) lsum[r] += __expf(sreg[i][r] - gmax[r]);
    }
#pragma unroll
    for (int off = 8; off >= 1; off >>= 1) {
#pragma unroll
        for (int r = 0; r < 4; r++) lsum[r] += __shfl_xor(lsum[r], off, 64);
    }
    if (r16 == 0) {
#pragma unroll
        for (int r = 0; r < 4; r++) reds[wave][quad * 4 + r] = lsum[r];
    }
    __syncthreads();

    float scale[4];
#pragma unroll
    for (int r = 0; r < 4; r++) {
        float s = reds[0][quad * 4 + r] + reds[1][quad * 4 + r] +
                  reds[2][quad * 4 + r] + reds[3][quad * 4 + r];
        scale[r] = QMp[bq + quad * 4 + r] / s;
    }

    // ---- write attn (fp32 global) + P (bf16 LDS) ----
#pragma unroll
    for (int i = 0; i < 16; i++) {
        const int col = kt0 + i * 16 + r16;
#pragma unroll
        for (int r = 0; r < 4; r++) {
            float v = __expf(sreg[i][r] - gmax[r]) * scale[r];
            out_attn[(bq + quad * 4 + r) * TK + col] = v;
            Pb[(quad * 4 + r) * PSTR + col] = f2bf_rn(v);
        }
    }
    __syncthreads();

    // ---- PV: wave w owns d-columns [w*16, w*16+16); V gathered from global ----
    const int dsl = wave * 16;
    floatx4 racc = {0.f, 0.f, 0.f, 0.f};
    {
        // lane reads V[k = c*32 + quad*8 + j][dsl + r16]
        const float* vbase = Vp + ((size_t)b * TK + quad * 8) * DKD + dsl + r16;
        float cur[8];
#pragma unroll
        for (int j = 0; j < 8; j++) cur[j] = vbase[j * DKD];

#pragma unroll 2
        for (int c = 0; c < 32; c++) {
            const int cn = (c + 1) & 31;  // wraps on last (harmless reload)
            float nxt[8];
#pragma unroll
            for (int j = 0; j < 8; j++) nxt[j] = vbase[(cn * 32 + j) * DKD];

            U8 vf;
#pragma unroll
            for (int p = 0; p < 4; p++)
                vf.u[p] = ((unsigned)f2bf_rn(cur[2 * p + 1]) << 16) |
                          (unsigned)f2bf_rn(cur[2 * p]);

            short8 pf = *(const short8*)(&Pb[r16 * PSTR + c * 32 + quad * 8]);
            racc = __builtin_amdgcn_mfma_f32_16x16x32_bf16(pf, vf.s, racc, 0, 0, 0);

#pragma unroll
            for (int j = 0; j < 8; j++) cur[j] = nxt[j];
        }
    }

#pragma unroll
    for (int r = 0; r < 4; r++)
        out_res[(bq + quad * 4 + r) * DKD + dsl + r16] = racc[r];
}

extern "C" void kernel_launch(void* const* d_in, const int* in_sizes, int n_in,
                              void* d_out, int out_size, void* d_ws, size_t ws_size,
                              hipStream_t stream) {
    const float* Kp  = (const float*)d_in[0];
    const float* Vp  = (const float*)d_in[1];
    const float* Qp  = (const float*)d_in[2];
    const int*   Mp  = (const int*)d_in[3];
    const float* QMp = (const float*)d_in[4];

    float* out      = (float*)d_out;
    float* out_res  = out;                              // [B,TQ,DK]
    float* out_attn = out + (size_t)NB * TQ * DKD;      // [B,TQ,TK]

    dim3 grid(NB * (TQ / TILE_Q));   // 2048 blocks
    dim3 block(256);
    attn_mfma_kernel<<<grid, block, 0, stream>>>(Kp, Vp, Qp, Mp, QMp, out_res, out_attn);
}